// Round 2
// baseline (187.763 us; speedup 1.0000x reference)
//
#include <hip/hip_runtime.h>
#include <math.h>

// AdaFace margin kernel, MI355X.
// Reference math (T_ALPHA = 1.0 => batch buffers BM0/BS0 vanish):
//   safe = clip(norms, 1e-3, 100); mean = safe.mean(); std = safe.std(ddof=1)
//   ms   = clip((safe - mean) / (std + 1e-3) * 0.333, -1, 1)
//   theta = acos(cosine); theta[r, lab] += -0.4*ms (valid rows)
//   theta = clip(theta, EPS, pi-EPS) on valid rows; cos_m = cos(theta)
//   cos_m[r, lab] -= 0.4 + 0.4*ms;  out = cos_m * 64
// For non-label columns on valid rows: cos(clip(acos(x))) == clip(x, -cosEPS, cosEPS).
// Invalid rows (label == -1): out = x * 64 (cos(acos(x)) identity, no clip).

#define MARGIN    0.4f
#define HPARAM    0.333f
#define SCALE     64.0f
#define EPSF      1e-3f
#define COS_EPS   0.999999500000041653f   // cos(1e-3)
#define PI_M_EPS  3.140592653589793f      // pi - 1e-3

__global__ __launch_bounds__(256) void stats_kernel(const float* __restrict__ norms,
                                                    int N, float* __restrict__ ws) {
    __shared__ double sdata[256];
    const int t = threadIdx.x;

    // pass 1: sum
    double s = 0.0;
    for (int i = t; i < N; i += 256) {
        float v = fminf(fmaxf(norms[i], 1e-3f), 100.0f);
        s += (double)v;
    }
    sdata[t] = s;
    __syncthreads();
    for (int k = 128; k > 0; k >>= 1) {
        if (t < k) sdata[t] += sdata[t + k];
        __syncthreads();
    }
    const double mean = sdata[0] / (double)N;
    __syncthreads();

    // pass 2: sum of squared deviations (unbiased std, ddof=1)
    double sq = 0.0;
    for (int i = t; i < N; i += 256) {
        float v = fminf(fmaxf(norms[i], 1e-3f), 100.0f);
        double d = (double)v - mean;
        sq += d * d;
    }
    sdata[t] = sq;
    __syncthreads();
    for (int k = 128; k > 0; k >>= 1) {
        if (t < k) sdata[t] += sdata[t + k];
        __syncthreads();
    }
    if (t == 0) {
        ws[0] = (float)mean;
        ws[1] = (float)sqrt(sdata[0] / (double)(N - 1));
    }
}

__global__ __launch_bounds__(256) void adaface_kernel(
        const float* __restrict__ cosine,
        const float* __restrict__ norms,
        const int*   __restrict__ label,
        const float* __restrict__ ws,
        float*       __restrict__ out,
        int C) {
    const int row  = blockIdx.y;
    const int c4   = blockIdx.x * blockDim.x + threadIdx.x;
    const int base = c4 * 4;
    if (base >= C) return;

    const int  lab   = label[row];
    const bool valid = (lab != -1);

    const size_t off = (size_t)row * (size_t)C + (size_t)base;
    const float4 x = *reinterpret_cast<const float4*>(cosine + off);
    float4 y;

    if (valid) {
        y.x = fminf(fmaxf(x.x, -COS_EPS), COS_EPS) * SCALE;
        y.y = fminf(fmaxf(x.y, -COS_EPS), COS_EPS) * SCALE;
        y.z = fminf(fmaxf(x.z, -COS_EPS), COS_EPS) * SCALE;
        y.w = fminf(fmaxf(x.w, -COS_EPS), COS_EPS) * SCALE;

        if (lab >= base && lab < base + 4) {
            // per-row margin scaler (tiny reads; norms/ws/label are L2-resident)
            const float bm = ws[0];
            const float bs = ws[1];
            const float sn = fminf(fmaxf(norms[row], 1e-3f), 100.0f);
            const float ms = fminf(fmaxf((sn - bm) / (bs + EPSF) * HPARAM, -1.0f), 1.0f);

            const int k = lab - base;
            const float xv = (&x.x)[k];
            float theta = acosf(xv) - MARGIN * ms;           // + g_angular
            theta = fminf(fmaxf(theta, EPSF), PI_M_EPS);     // clip
            const float g_add = MARGIN + MARGIN * ms;
            (&y.x)[k] = (cosf(theta) - g_add) * SCALE;
        }
    } else {
        // invalid row: cos(acos(x)) == x, no clip
        y.x = x.x * SCALE;
        y.y = x.y * SCALE;
        y.z = x.z * SCALE;
        y.w = x.w * SCALE;
    }

    *reinterpret_cast<float4*>(out + off) = y;
}

extern "C" void kernel_launch(void* const* d_in, const int* in_sizes, int n_in,
                              void* d_out, int out_size, void* d_ws, size_t ws_size,
                              hipStream_t stream) {
    const float* cosine = (const float*)d_in[0];
    const float* norms  = (const float*)d_in[1];
    const int*   label  = (const int*)d_in[2];
    float*       out    = (float*)d_out;
    float*       ws     = (float*)d_ws;

    const int N = in_sizes[2];            // 2048
    const int C = in_sizes[0] / N;        // 50000

    stats_kernel<<<1, 256, 0, stream>>>(norms, N, ws);

    const int c4      = (C + 3) / 4;                  // float4s per row
    const int gx      = (c4 + 255) / 256;
    dim3 grid(gx, N, 1);
    adaface_kernel<<<grid, 256, 0, stream>>>(cosine, norms, label, ws, out, C);
}

// Round 3
// 185.918 us; speedup vs baseline: 1.0099x; 1.0099x over previous
//
#include <hip/hip_runtime.h>
#include <math.h>

// AdaFace margin kernel, MI355X — round 3.
// Structure:
//   prep_kernel (1 block): mean/std of clip(norms) + per-row corrected label value -> ws
//   main_kernel (1 block/row, 2048 blocks x 256 thr = 32 waves/CU): pure
//     clip(x,±cos(eps))*64 stream with one compare to splice in ws[2+row].
// Math identities (T_ALPHA=1 kills BM0/BS0):
//   non-label cols, valid rows:  cos(clip(acos(x),e,pi-e)) == clip(x,-cos e, cos e)
//   invalid rows (label==-1):    out = x*64 exactly.

#define MARGIN    0.4f
#define HPARAM    0.333f
#define SCALE     64.0f
#define EPSF      1e-3f
#define COS_EPS   0.999999500000041653f   // cos(1e-3)
#define PI_M_EPS  3.140592653589793f      // pi - 1e-3

typedef float f32x4 __attribute__((ext_vector_type(4)));

__global__ __launch_bounds__(256) void prep_kernel(const float* __restrict__ norms,
                                                   const int*   __restrict__ label,
                                                   const float* __restrict__ cosine,
                                                   int N, int C,
                                                   float* __restrict__ ws) {
    __shared__ double sdata[256];
    const int t = threadIdx.x;

    // mean of clip(norms, 1e-3, 100)
    double s = 0.0;
    for (int i = t; i < N; i += 256) {
        float v = fminf(fmaxf(norms[i], 1e-3f), 100.0f);
        s += (double)v;
    }
    sdata[t] = s;
    __syncthreads();
    for (int k = 128; k > 0; k >>= 1) {
        if (t < k) sdata[t] += sdata[t + k];
        __syncthreads();
    }
    const double mean = sdata[0] / (double)N;
    __syncthreads();

    // unbiased std (ddof=1)
    double sq = 0.0;
    for (int i = t; i < N; i += 256) {
        float v = fminf(fmaxf(norms[i], 1e-3f), 100.0f);
        double d = (double)v - mean;
        sq += d * d;
    }
    sdata[t] = sq;
    __syncthreads();
    for (int k = 128; k > 0; k >>= 1) {
        if (t < k) sdata[t] += sdata[t + k];
        __syncthreads();
    }
    const float bm = (float)mean;
    const float bs = (float)sqrt(sdata[0] / (double)(N - 1));
    if (t == 0) { ws[0] = bm; ws[1] = bs; }
    __syncthreads();

    // per-row corrected label value (scattered gather of 2048 elements)
    for (int row = t; row < N; row += 256) {
        const int lab = label[row];
        float fix = 0.0f;
        if (lab != -1) {
            const float sn = fminf(fmaxf(norms[row], 1e-3f), 100.0f);
            const float ms = fminf(fmaxf((sn - bm) / (bs + EPSF) * HPARAM, -1.0f), 1.0f);
            const float xv = cosine[(size_t)row * (size_t)C + (size_t)lab];
            float theta = acosf(xv) - MARGIN * ms;           // + g_angular
            theta = fminf(fmaxf(theta, EPSF), PI_M_EPS);     // clip (valid rows)
            fix = (cosf(theta) - (MARGIN + MARGIN * ms)) * SCALE;
        }
        ws[2 + row] = fix;
    }
}

__global__ __launch_bounds__(256) void adaface_main(
        const float* __restrict__ cosine,
        const int*   __restrict__ label,
        const float* __restrict__ ws,
        float*       __restrict__ out,
        int C4) {
    const int row = blockIdx.x;
    const int lab = label[row];
    const bool valid = (lab != -1);
    const int lab4 = lab >> 2;          // float4 index of the label column
    const int labk = lab & 3;
    const float fix = ws[2 + row];

    const f32x4* __restrict__ src = reinterpret_cast<const f32x4*>(cosine) + (size_t)row * (size_t)C4;
    f32x4*       __restrict__ dst = reinterpret_cast<f32x4*>(out)          + (size_t)row * (size_t)C4;

    if (valid) {
        for (int c4 = threadIdx.x; c4 < C4; c4 += 256) {
            f32x4 x = __builtin_nontemporal_load(src + c4);
            f32x4 y;
            y.x = fminf(fmaxf(x.x, -COS_EPS), COS_EPS) * SCALE;
            y.y = fminf(fmaxf(x.y, -COS_EPS), COS_EPS) * SCALE;
            y.z = fminf(fmaxf(x.z, -COS_EPS), COS_EPS) * SCALE;
            y.w = fminf(fmaxf(x.w, -COS_EPS), COS_EPS) * SCALE;
            if (c4 == lab4) {           // one thread, one iteration per row
                y.x = (labk == 0) ? fix : y.x;
                y.y = (labk == 1) ? fix : y.y;
                y.z = (labk == 2) ? fix : y.z;
                y.w = (labk == 3) ? fix : y.w;
            }
            __builtin_nontemporal_store(y, dst + c4);
        }
    } else {
        for (int c4 = threadIdx.x; c4 < C4; c4 += 256) {
            f32x4 x = __builtin_nontemporal_load(src + c4);
            f32x4 y = { x.x * SCALE, x.y * SCALE, x.z * SCALE, x.w * SCALE };
            __builtin_nontemporal_store(y, dst + c4);
        }
    }
}

extern "C" void kernel_launch(void* const* d_in, const int* in_sizes, int n_in,
                              void* d_out, int out_size, void* d_ws, size_t ws_size,
                              hipStream_t stream) {
    const float* cosine = (const float*)d_in[0];
    const float* norms  = (const float*)d_in[1];
    const int*   label  = (const int*)d_in[2];
    float*       out    = (float*)d_out;
    float*       ws     = (float*)d_ws;

    const int N  = in_sizes[2];            // 2048
    const int C  = in_sizes[0] / N;        // 50000
    const int C4 = C / 4;                  // 12500 (C divisible by 4)

    prep_kernel<<<1, 256, 0, stream>>>(norms, label, cosine, N, C, ws);
    adaface_main<<<N, 256, 0, stream>>>(cosine, label, ws, out, C4);
}

// Round 4
// 184.314 us; speedup vs baseline: 1.0187x; 1.0087x over previous
//
#include <hip/hip_runtime.h>
#include <math.h>

// AdaFace margin kernel, MI355X — round 4: single fused kernel.
// Every block (one per row, 2048 x 256 = exactly 32 waves/CU, whole grid
// co-resident) redundantly computes the norms mean/std (8 KB, L2-resident),
// the owner thread computes the corrected label value, then the block streams
// its 400 KB row as clip(x,±cos(1e-3))*64 with a 2-wide unrolled float4 loop.
// Identities (T_ALPHA=1 kills BM0/BS0):
//   valid rows, non-label cols: cos(clip(acos(x),e,pi-e)) == clip(x,-cos e,cos e)
//   invalid rows (label==-1):   out = x*64 exactly.

#define MARGIN    0.4f
#define HPARAM    0.333f
#define SCALE     64.0f
#define EPSF      1e-3f
#define COS_EPS   0.999999500000041653f   // cos(1e-3)
#define PI_M_EPS  3.140592653589793f      // pi - 1e-3

typedef float f32x4 __attribute__((ext_vector_type(4)));

__device__ __forceinline__ f32x4 clipscale(f32x4 x) {
    f32x4 y;
    y.x = fminf(fmaxf(x.x, -COS_EPS), COS_EPS) * SCALE;
    y.y = fminf(fmaxf(x.y, -COS_EPS), COS_EPS) * SCALE;
    y.z = fminf(fmaxf(x.z, -COS_EPS), COS_EPS) * SCALE;
    y.w = fminf(fmaxf(x.w, -COS_EPS), COS_EPS) * SCALE;
    return y;
}

__global__ __launch_bounds__(256) void adaface_fused(
        const float* __restrict__ cosine,
        const float* __restrict__ norms,
        const int*   __restrict__ label,
        float*       __restrict__ out,
        int N, int C, int C4) {
    const int t   = threadIdx.x;
    const int row = blockIdx.x;
    const int lab = label[row];

    const f32x4* __restrict__ src = reinterpret_cast<const f32x4*>(cosine) + (size_t)row * (size_t)C4;
    f32x4*       __restrict__ dst = reinterpret_cast<f32x4*>(out)          + (size_t)row * (size_t)C4;

    if (lab != -1) {
        // ---- redundant per-block stats over clip(norms, 1e-3, 100) ----
        __shared__ double sdata[256];
        double s = 0.0;
        for (int i = t; i < N; i += 256)
            s += (double)fminf(fmaxf(norms[i], 1e-3f), 100.0f);
        sdata[t] = s;
        __syncthreads();
        for (int k = 128; k > 0; k >>= 1) {
            if (t < k) sdata[t] += sdata[t + k];
            __syncthreads();
        }
        const double mean = sdata[0] / (double)N;
        __syncthreads();
        double sq = 0.0;
        for (int i = t; i < N; i += 256) {
            double d = (double)fminf(fmaxf(norms[i], 1e-3f), 100.0f) - mean;
            sq += d * d;
        }
        sdata[t] = sq;
        __syncthreads();
        for (int k = 128; k > 0; k >>= 1) {
            if (t < k) sdata[t] += sdata[t + k];
            __syncthreads();
        }
        const float bm = (float)mean;
        const float bs = (float)sqrt(sdata[0] / (double)(N - 1));

        // ---- owner thread computes the corrected label value ----
        const int lab4 = lab >> 2;
        const int labk = lab & 3;
        float fix = 0.0f;
        if (t == (lab4 & 255)) {                 // lab4 % blockDim
            const float sn = fminf(fmaxf(norms[row], 1e-3f), 100.0f);
            const float ms = fminf(fmaxf((sn - bm) / (bs + EPSF) * HPARAM, -1.0f), 1.0f);
            const float xv = cosine[(size_t)row * (size_t)C + (size_t)lab];
            float theta = acosf(xv) - MARGIN * ms;          // + g_angular
            theta = fminf(fmaxf(theta, EPSF), PI_M_EPS);    // clip
            fix = (cosf(theta) - (MARGIN + MARGIN * ms)) * SCALE;
        }

        // ---- 2-wide unrolled stream ----
        int c4 = t;
        for (; c4 + 256 < C4; c4 += 512) {
            f32x4 x0 = src[c4];
            f32x4 x1 = src[c4 + 256];
            f32x4 y0 = clipscale(x0);
            f32x4 y1 = clipscale(x1);
            if (c4 == lab4) {
                y0.x = (labk == 0) ? fix : y0.x;
                y0.y = (labk == 1) ? fix : y0.y;
                y0.z = (labk == 2) ? fix : y0.z;
                y0.w = (labk == 3) ? fix : y0.w;
            }
            if (c4 + 256 == lab4) {
                y1.x = (labk == 0) ? fix : y1.x;
                y1.y = (labk == 1) ? fix : y1.y;
                y1.z = (labk == 2) ? fix : y1.z;
                y1.w = (labk == 3) ? fix : y1.w;
            }
            dst[c4]       = y0;
            dst[c4 + 256] = y1;
        }
        for (; c4 < C4; c4 += 256) {
            f32x4 y = clipscale(src[c4]);
            if (c4 == lab4) {
                y.x = (labk == 0) ? fix : y.x;
                y.y = (labk == 1) ? fix : y.y;
                y.z = (labk == 2) ? fix : y.z;
                y.w = (labk == 3) ? fix : y.w;
            }
            dst[c4] = y;
        }
    } else {
        // invalid row: out = x * 64 exactly
        int c4 = t;
        for (; c4 + 256 < C4; c4 += 512) {
            f32x4 x0 = src[c4];
            f32x4 x1 = src[c4 + 256];
            f32x4 y0 = { x0.x * SCALE, x0.y * SCALE, x0.z * SCALE, x0.w * SCALE };
            f32x4 y1 = { x1.x * SCALE, x1.y * SCALE, x1.z * SCALE, x1.w * SCALE };
            dst[c4]       = y0;
            dst[c4 + 256] = y1;
        }
        for (; c4 < C4; c4 += 256) {
            f32x4 x = src[c4];
            f32x4 y = { x.x * SCALE, x.y * SCALE, x.z * SCALE, x.w * SCALE };
            dst[c4] = y;
        }
    }
}

extern "C" void kernel_launch(void* const* d_in, const int* in_sizes, int n_in,
                              void* d_out, int out_size, void* d_ws, size_t ws_size,
                              hipStream_t stream) {
    const float* cosine = (const float*)d_in[0];
    const float* norms  = (const float*)d_in[1];
    const int*   label  = (const int*)d_in[2];
    float*       out    = (float*)d_out;

    const int N  = in_sizes[2];            // 2048
    const int C  = in_sizes[0] / N;        // 50000
    const int C4 = C / 4;                  // 12500

    adaface_fused<<<N, 256, 0, stream>>>(cosine, norms, label, out, N, C, C4);
}